// Round 6
// baseline (55.463 us; speedup 1.0000x reference)
//
#include <hip/hip_runtime.h>

#define COLS 8192
#define TPB  256

// One block per row, 5 barrier phases via pairwise level fusion:
// P0: analysis lev0+lev1 fused (a0 recomputed in registers from x window)
//     -> d0,d1 global; d1 also LDS F; a1 -> LDS C.
// P1: analysis lev2+lev3 fused -> d2,d3 global+LDS D; a3 -> LDS E.
// P2: wave-0 tail: analysis lev4..7 + synth lev7..4 (in-wave ordering)
//     -> d4..d7,approx global+D; rec4 -> E.
// P3: synth lev3+lev2 fused (rec3 recomputed in registers) -> rec2 in C.
// P4: synth lev1+lev0 fused (rec1 recomputed in registers; d0 re-read L2-hot,
//     d1 from F, rec2 from C) -> out_rec global.
__global__ __launch_bounds__(TPB, 6) void despawn_kernel(
    const float* __restrict__ x, const float* __restrict__ scaling,
    float* __restrict__ out, int rows)
{
    __shared__ __align__(16) float C[2048];   // a1 -> tail scratch -> rec2
    __shared__ __align__(16) float D[2048];   // d2(1024)|d3(512)|d4(256)|d5(128)|d6(64)|d7(32)|approx(32)
    __shared__ __align__(16) float E[512];    // a3 -> rec4
    __shared__ __align__(16) float F[2048];   // d1 copy for P4
    __shared__ float filt[32];

    const int row = blockIdx.x;
    const int tid = threadIdx.x;
    if (tid < 32) filt[tid] = scaling[tid];
    __syncthreads();

    const float* __restrict__ xg       = x + (size_t)row * COLS;
    float* __restrict__       out_rec  = out + (size_t)row * COLS;
    float* __restrict__       out_coef = out + (size_t)rows * COLS + (size_t)row * COLS;

    // ---------------- P0: fused analysis lev0 + lev1 ----------------
    // d0[k]=g0*x[2k]+g1*x[2k-1]+g2*x[2k-2]+g3*x[2k-3]; a0 likewise with h.
    // d1/a1 from a0 with lev1 filters. Chunk c covers x[16c..16c+15].
    {
        const float h0=filt[0],h1=filt[1],h2=filt[2],h3=filt[3];
        const float g0=h3,g1=-h2,g2=h1,g3=-h0;
        const float H0=filt[4],H1=filt[5],H2=filt[6],H3=filt[7];
        const float G0=H3,G1=-H2,G2=H1,G3=-H0;
        const float4* __restrict__ xg4 = reinterpret_cast<const float4*>(xg);
        float4* __restrict__ o_d0 = reinterpret_cast<float4*>(out_coef);
        float4* __restrict__ o_d1 = reinterpret_cast<float4*>(out_coef + 4096);
        float4* a1_4 = reinterpret_cast<float4*>(C);
        float4* f4   = reinterpret_cast<float4*>(F);
        for (int c = tid; c < 512; c += TPB) {
            // xv[i] = x[16c-12+i], i in [0,28): covers needed [16c-9, 16c+14]
            float xv[28];
            #pragma unroll
            for (int q = 0; q < 7; ++q) {
                const float4 v = xg4[(4*c - 3 + q) & 2047];
                xv[4*q]=v.x; xv[4*q+1]=v.y; xv[4*q+2]=v.z; xv[4*q+3]=v.w;
            }
            float dv[8];                       // d0[8c+u]
            #pragma unroll
            for (int u = 0; u < 8; ++u)
                dv[u] = g0*xv[2*u+12] + g1*xv[2*u+11] + g2*xv[2*u+10] + g3*xv[2*u+9];
            o_d0[2*c]   = make_float4(dv[0],dv[1],dv[2],dv[3]);
            o_d0[2*c+1] = make_float4(dv[4],dv[5],dv[6],dv[7]);
            float A[11];                       // a0[8c-3+wi]
            #pragma unroll
            for (int wi = 0; wi < 11; ++wi)
                A[wi] = h0*xv[2*wi+6] + h1*xv[2*wi+5] + h2*xv[2*wi+4] + h3*xv[2*wi+3];
            float d1v[4], a1v[4];              // [4c+u]
            #pragma unroll
            for (int u = 0; u < 4; ++u) {
                d1v[u] = G0*A[2*u+3] + G1*A[2*u+2] + G2*A[2*u+1] + G3*A[2*u];
                a1v[u] = H0*A[2*u+3] + H1*A[2*u+2] + H2*A[2*u+1] + H3*A[2*u];
            }
            const float4 d1q = make_float4(d1v[0],d1v[1],d1v[2],d1v[3]);
            o_d1[c] = d1q;
            f4[c]   = d1q;
            a1_4[c] = make_float4(a1v[0],a1v[1],a1v[2],a1v[3]);
        }
        __syncthreads();
    }

    // ---------------- P1: fused analysis lev2 + lev3 ----------------
    // Thread t covers a1[8t..8t+7]: d2[4t..4t+3], d3[2t..2t+1], a3[2t..2t+1].
    {
        const float h0=filt[8],h1=filt[9],h2=filt[10],h3=filt[11];
        const float g0=h3,g1=-h2,g2=h1,g3=-h0;
        const float H0=filt[12],H1=filt[13],H2=filt[14],H3=filt[15];
        const float G0=H3,G1=-H2,G2=H1,G3=-H0;
        const int t = tid;
        const float4* C4 = reinterpret_cast<const float4*>(C);
        float av[20];                          // av[i] = a1[8t-12+i]
        #pragma unroll
        for (int q = 0; q < 5; ++q) {
            const float4 v = C4[(2*t - 3 + q) & 511];
            av[4*q]=v.x; av[4*q+1]=v.y; av[4*q+2]=v.z; av[4*q+3]=v.w;
        }
        float d2v[4];
        #pragma unroll
        for (int u = 0; u < 4; ++u)
            d2v[u] = g0*av[2*u+12] + g1*av[2*u+11] + g2*av[2*u+10] + g3*av[2*u+9];
        float A2[6];                           // a2[4t-3+wi]
        #pragma unroll
        for (int wi = 0; wi < 6; ++wi)
            A2[wi] = h0*av[2*wi+6] + h1*av[2*wi+5] + h2*av[2*wi+4] + h3*av[2*wi+3];
        float d3v[2], a3v[2];
        #pragma unroll
        for (int u = 0; u < 2; ++u) {
            d3v[u] = G0*A2[2*u+3] + G1*A2[2*u+2] + G2*A2[2*u+1] + G3*A2[2*u];
            a3v[u] = H0*A2[2*u+3] + H1*A2[2*u+2] + H2*A2[2*u+1] + H3*A2[2*u];
        }
        const float4 d2q = make_float4(d2v[0],d2v[1],d2v[2],d2v[3]);
        reinterpret_cast<float4*>(D)[t] = d2q;
        reinterpret_cast<float4*>(out_coef + 6144)[t] = d2q;
        const float2 d3q = make_float2(d3v[0], d3v[1]);
        reinterpret_cast<float2*>(D + 1024)[t] = d3q;
        reinterpret_cast<float2*>(out_coef + 7168)[t] = d3q;
        reinterpret_cast<float2*>(E)[t] = make_float2(a3v[0], a3v[1]);
        __syncthreads();
    }

    // ---------------- P2: wave-0 tail (lev4..7 both directions) -----
    if (tid < 64) {
        {   // analysis lev4..7
            float* pin[4] = {E, C, C + 256, C + 384};
            int nn = 512, coffW = 7680, dW = 1536;
            for (int lev = 4; lev <= 7; ++lev) {
                const float h0=filt[4*lev],h1=filt[4*lev+1],h2=filt[4*lev+2],h3=filt[4*lev+3];
                const float g0=h3,g1=-h2,g2=h1,g3=-h0;
                const int half = nn >> 1, mask = nn - 1;
                const float* ac = pin[lev - 4];
                float* an = (lev == 7) ? (D + 2016) : pin[lev - 3];
                for (int i = tid; i < half; i += 64) {
                    const int b = 2 * i;
                    const float x0 = ac[b];
                    const float x1 = ac[(b - 1) & mask];
                    const float x2 = ac[(b - 2) & mask];
                    const float x3 = ac[(b - 3) & mask];
                    const float d = g0*x0 + g1*x1 + g2*x2 + g3*x3;
                    const float a = h0*x0 + h1*x1 + h2*x2 + h3*x3;
                    D[dW + i] = d;
                    out_coef[coffW + i] = d;
                    an[i] = a;
                    if (lev == 7) out_coef[8160 + i] = a;
                }
                __builtin_amdgcn_wave_barrier();
                coffW += half; dW += half; nn = half;
            }
        }
        {   // synth lev7..4 -> rec4 in E
            int mS = 32, dS = 1984;
            const float* ap = D + 2016;
            float* recT[4] = {C, C + 64, C + 192, E};
            for (int lev = 7; lev >= 4; --lev) {
                const float h0=filt[4*lev],h1=filt[4*lev+1],h2=filt[4*lev+2],h3=filt[4*lev+3];
                const float g0=h3,g1=-h2,g2=h1,g3=-h0;
                const int mm = mS - 1;
                const float* dd = D + dS;
                float* rec = recT[7 - lev];
                for (int j = tid; j < mS; j += 64) {
                    const float dj=dd[j], dj1=dd[(j+1)&mm], dj2=dd[(j+2)&mm];
                    const float aj=ap[j], aj1=ap[(j+1)&mm], aj2=ap[(j+2)&mm];
                    rec[2*j]   = g0*dj  + g2*dj1 + h0*aj  + h2*aj1;
                    rec[2*j+1] = g1*dj1 + g3*dj2 + h1*aj1 + h3*aj2;
                }
                __builtin_amdgcn_wave_barrier();
                ap = rec; mS <<= 1; dS -= mS;
            }
        }
    }
    __syncthreads();

    // ---------------- P3: fused synth lev3 + lev2 -> rec2 in C ------
    // Thread t produces rec2[8t..8t+7]; rec3 values recomputed in registers.
    {
        const float th0=filt[12],th1=filt[13],th2=filt[14],th3=filt[15];
        const float tg0=th3,tg1=-th2,tg2=th1,tg3=-th0;
        const float ch0=filt[8],ch1=filt[9],ch2=filt[10],ch3=filt[11];
        const float cg0=ch3,cg1=-ch2,cg2=ch1,cg3=-ch0;
        const int t = tid;
        float d3v[5], ev[5];                   // d3/rec4 [2t..2t+4] mod 512
        #pragma unroll
        for (int i = 0; i < 5; ++i) {
            const int idx = (2*t + i) & 511;
            d3v[i] = D[1024 + idx];
            ev[i]  = E[idx];
        }
        float r3[6];                           // rec3[4t..4t+5]
        #pragma unroll
        for (int e = 0; e < 6; ++e) {
            const int j = e >> 1;
            r3[e] = (e & 1) ? (tg1*d3v[j+1] + tg3*d3v[j+2] + th1*ev[j+1] + th3*ev[j+2])
                            : (tg0*d3v[j]   + tg2*d3v[j+1] + th0*ev[j]   + th2*ev[j+1]);
        }
        float d2v[8];                          // d2[4t..4t+7] (need ..+5), mod 1024
        const float4* D4 = reinterpret_cast<const float4*>(D);
        #pragma unroll
        for (int q = 0; q < 2; ++q) {
            const float4 v = D4[(t + q) & 255];
            d2v[4*q]=v.x; d2v[4*q+1]=v.y; d2v[4*q+2]=v.z; d2v[4*q+3]=v.w;
        }
        float o[8];
        #pragma unroll
        for (int e = 0; e < 4; ++e) {
            o[2*e]   = cg0*d2v[e]   + cg2*d2v[e+1] + ch0*r3[e]   + ch2*r3[e+1];
            o[2*e+1] = cg1*d2v[e+1] + cg3*d2v[e+2] + ch1*r3[e+1] + ch3*r3[e+2];
        }
        reinterpret_cast<float4*>(C)[2*t]   = make_float4(o[0],o[1],o[2],o[3]);
        reinterpret_cast<float4*>(C)[2*t+1] = make_float4(o[4],o[5],o[6],o[7]);
    }
    __syncthreads();

    // ---------------- P4: fused synth lev1 + lev0 -> out_rec --------
    // Chunk c produces rec0[16c..16c+15]; rec1 recomputed in registers.
    {
        const float uh0=filt[4],uh1=filt[5],uh2=filt[6],uh3=filt[7];
        const float ug0=uh3,ug1=-uh2,ug2=uh1,ug3=-uh0;
        const float zh0=filt[0],zh1=filt[1],zh2=filt[2],zh3=filt[3];
        const float zg0=zh3,zg1=-zh2,zg2=zh1,zg3=-zh0;
        const float4* __restrict__ d0g = reinterpret_cast<const float4*>(out_coef);
        const float4* F4 = reinterpret_cast<const float4*>(F);
        const float4* C4 = reinterpret_cast<const float4*>(C);
        float4* __restrict__ o4 = reinterpret_cast<float4*>(out_rec);
        for (int c = tid; c < 512; c += TPB) {
            float d0v[12];                     // d0[8c..8c+11] (need ..+9), mod 4096
            #pragma unroll
            for (int q = 0; q < 3; ++q) {
                const float4 v = d0g[(2*c + q) & 1023];
                d0v[4*q]=v.x; d0v[4*q+1]=v.y; d0v[4*q+2]=v.z; d0v[4*q+3]=v.w;
            }
            float d1v[8], r2v[8];              // d1/rec2 [4c..4c+7] (need ..+6), mod 2048
            #pragma unroll
            for (int q = 0; q < 2; ++q) {
                const float4 v = F4[(c + q) & 511];
                d1v[4*q]=v.x; d1v[4*q+1]=v.y; d1v[4*q+2]=v.z; d1v[4*q+3]=v.w;
                const float4 w = C4[(c + q) & 511];
                r2v[4*q]=w.x; r2v[4*q+1]=w.y; r2v[4*q+2]=w.z; r2v[4*q+3]=w.w;
            }
            float r1[10];                      // rec1[8c..8c+9]
            #pragma unroll
            for (int e = 0; e < 10; ++e) {
                const int j = e >> 1;
                r1[e] = (e & 1) ? (ug1*d1v[j+1] + ug3*d1v[j+2] + uh1*r2v[j+1] + uh3*r2v[j+2])
                                : (ug0*d1v[j]   + ug2*d1v[j+1] + uh0*r2v[j]   + uh2*r2v[j+1]);
            }
            #pragma unroll
            for (int e = 0; e < 8; e += 2) {
                const float a0_ = zg0*d0v[e]   + zg2*d0v[e+1] + zh0*r1[e]   + zh2*r1[e+1];
                const float a1_ = zg1*d0v[e+1] + zg3*d0v[e+2] + zh1*r1[e+1] + zh3*r1[e+2];
                const float a2_ = zg0*d0v[e+1] + zg2*d0v[e+2] + zh0*r1[e+1] + zh2*r1[e+2];
                const float a3_ = zg1*d0v[e+2] + zg3*d0v[e+3] + zh1*r1[e+2] + zh3*r1[e+3];
                o4[4*c + (e >> 1)] = make_float4(a0_, a1_, a2_, a3_);
            }
        }
    }
}

extern "C" void kernel_launch(void* const* d_in, const int* in_sizes, int n_in,
                              void* d_out, int out_size, void* d_ws, size_t ws_size,
                              hipStream_t stream) {
    const float* x       = (const float*)d_in[0];
    const float* scaling = (const float*)d_in[1];
    float* out           = (float*)d_out;
    const int rows = in_sizes[0] / COLS;
    despawn_kernel<<<rows, TPB, 0, stream>>>(x, scaling, out, rows);
}

// Round 7
// 42.764 us; speedup vs baseline: 1.2970x; 1.2970x over previous
//
#include <hip/hip_runtime.h>

#define COLS   8192
#define LEVELS 8
#define TPB    512

// LDS-only barrier: waits LDS ops, lets global (vmcnt) stores stay in flight
// across the phase chain (T4 idiom at block scope). Full __syncthreads() is
// used once, after the wave-0 tail, to drain coeff stores before synthesis
// re-reads them from global.
__device__ __forceinline__ void bar_lds() {
    asm volatile("s_waitcnt lgkmcnt(0)" ::: "memory");
    __builtin_amdgcn_sched_barrier(0);
    __builtin_amdgcn_s_barrier();
    __builtin_amdgcn_sched_barrier(0);
}

// One block per row.
// LDS: B(16K) + C(8K) approx ping-pong, D(8K) = details lev2..7 + final approx.
// Analysis lev0 reads x from global (float4); details lev0/1 go to global only
// (synthesis re-reads them L2-hot with high parallelism); details lev2..7 also
// kept in D so the latency-bound tail never touches global.
// Levels 4..7 (both directions) run on wave 0 only: in-wave LDS ordering.
__global__ __launch_bounds__(TPB) void despawn_kernel(
    const float* __restrict__ x, const float* __restrict__ scaling,
    float* __restrict__ out, int rows)
{
    __shared__ __align__(16) float B[COLS / 2];   // 16 KB
    __shared__ __align__(16) float C[COLS / 4];   // 8 KB
    __shared__ __align__(16) float D[COLS / 4];   // 8 KB
    __shared__ float filt[LEVELS * 4];

    const int row = blockIdx.x;
    const int tid = threadIdx.x;

    if (tid < LEVELS * 4) filt[tid] = scaling[tid];
    bar_lds();

    const float* __restrict__ xg       = x + (size_t)row * COLS;
    float* __restrict__       out_rec  = out + (size_t)row * COLS;
    float* __restrict__       out_coef = out + (size_t)rows * COLS + (size_t)row * COLS;

    // ---------------- analysis level 0 (global float4, 4 outputs/thread) ----
    // d[k] = g0*x[2k] + g1*x[2k-1] + g2*x[2k-2] + g3*x[2k-3]   (mod 8192)
    {
        const float h0 = filt[0], h1 = filt[1], h2 = filt[2], h3 = filt[3];
        const float g0 = h3, g1 = -h2, g2 = h1, g3 = -h0;
        const float4* __restrict__ xg4 = reinterpret_cast<const float4*>(xg);
        const int q8 = COLS / 8, qm = COLS / 4 - 1;
        for (int i = tid; i < q8; i += TPB) {
            const float4 va = xg4[(2 * i - 1) & qm];   // x[8i-4..8i-1]
            const float4 vb = xg4[2 * i];              // x[8i  ..8i+3]
            const float4 vc = xg4[2 * i + 1];          // x[8i+4..8i+7]
            float4 dv, av;
            dv.x = g0*vb.x + g1*va.w + g2*va.z + g3*va.y;
            av.x = h0*vb.x + h1*va.w + h2*va.z + h3*va.y;
            dv.y = g0*vb.z + g1*vb.y + g2*vb.x + g3*va.w;
            av.y = h0*vb.z + h1*vb.y + h2*vb.x + h3*va.w;
            dv.z = g0*vc.x + g1*vb.w + g2*vb.z + g3*vb.y;
            av.z = h0*vc.x + h1*vb.w + h2*vb.z + h3*vb.y;
            dv.w = g0*vc.z + g1*vc.y + g2*vc.x + g3*vb.w;
            av.w = h0*vc.z + h1*vc.y + h2*vc.x + h3*vb.w;
            reinterpret_cast<float4*>(out_coef)[i] = dv;   // stays in flight
            reinterpret_cast<float4*>(B)[i]        = av;
        }
        bar_lds();
    }

    // ---------------- analysis levels 1..3 (LDS float4, 4 outputs/thread) ---
    int n = COLS / 2, coff = COLS / 2, dOff = 0;
    float* cur = B;
    float* nxt = C;
    for (int lev = 1; lev <= 3; ++lev) {
        const float h0 = filt[4*lev+0], h1 = filt[4*lev+1],
                    h2 = filt[4*lev+2], h3 = filt[4*lev+3];
        const float g0 = h3, g1 = -h2, g2 = h1, g3 = -h0;
        const int half = n >> 1, qq = half >> 2, qm = (n >> 2) - 1;
        const float4* c4 = reinterpret_cast<const float4*>(cur);
        float4* o4 = reinterpret_cast<float4*>(out_coef + coff);
        float4* n4 = reinterpret_cast<float4*>(nxt);
        float4* D4 = reinterpret_cast<float4*>(D + dOff);
        const bool toD = (lev >= 2);
        for (int p = tid; p < qq; p += TPB) {
            const float4 va = c4[(2 * p - 1) & qm];
            const float4 vb = c4[2 * p];
            const float4 vc = c4[2 * p + 1];
            float4 dv, av;
            dv.x = g0*vb.x + g1*va.w + g2*va.z + g3*va.y;
            av.x = h0*vb.x + h1*va.w + h2*va.z + h3*va.y;
            dv.y = g0*vb.z + g1*vb.y + g2*vb.x + g3*va.w;
            av.y = h0*vb.z + h1*vb.y + h2*vb.x + h3*va.w;
            dv.z = g0*vc.x + g1*vb.w + g2*vb.z + g3*vb.y;
            av.z = h0*vc.x + h1*vb.w + h2*vb.z + h3*vb.y;
            dv.w = g0*vc.z + g1*vc.y + g2*vc.x + g3*vb.w;
            av.w = h0*vc.z + h1*vc.y + h2*vc.x + h3*vb.w;
            o4[p] = dv;            // stays in flight
            n4[p] = av;
            if (toD) D4[p] = dv;
        }
        bar_lds();
        coff += half;
        if (toD) dOff += half;
        n = half;
        float* t = cur; cur = nxt; nxt = t;
    }
    // approx(512) now in C (cur == C)

    // ---------------- wave-0 tail: levels 4..7 both directions --------------
    // D layout: lev2@0(1024) lev3@1024(512) lev4@1536(256) lev5@1792(128)
    //           lev6@1920(64) lev7@1984(32) approx@2016(32)
    if (tid < 64) {
        float* acur = C;
        float* anxt = B;
        int nn = 512, coffW = 7680, dW = 1536;
        for (int lev = 4; lev <= 7; ++lev) {
            const float h0 = filt[4*lev+0], h1 = filt[4*lev+1],
                        h2 = filt[4*lev+2], h3 = filt[4*lev+3];
            const float g0 = h3, g1 = -h2, g2 = h1, g3 = -h0;
            const int half = nn >> 1, mask = nn - 1;
            for (int i = tid; i < half; i += 64) {
                const int b = 2 * i;
                const float x0 = acur[b];
                const float x1 = acur[(b - 1) & mask];
                const float x2 = acur[(b - 2) & mask];
                const float x3 = acur[(b - 3) & mask];
                const float d = g0*x0 + g1*x1 + g2*x2 + g3*x3;
                const float a = h0*x0 + h1*x1 + h2*x2 + h3*x3;
                D[dW + i] = d;
                out_coef[coffW + i] = d;
                if (lev == 7) { D[2016 + i] = a; out_coef[8160 + i] = a; }
                else          anxt[i] = a;
            }
            __builtin_amdgcn_wave_barrier();
            coffW += half; dW += half; nn = half;
            float* t = acur; acur = anxt; anxt = t;
        }
        // synthesis lev7..4 (in-wave)
        int mS = 32, dS = 1984;
        const float* aprevW = D + 2016;
        for (int lev = 7; lev >= 4; --lev) {
            const float h0 = filt[4*lev+0], h1 = filt[4*lev+1],
                        h2 = filt[4*lev+2], h3 = filt[4*lev+3];
            const float g0 = h3, g1 = -h2, g2 = h1, g3 = -h0;
            const int mm = mS - 1;
            float* recW = (lev & 1) ? B : C;
            for (int j = tid; j < mS; j += 64) {
                const float dj  = D[dS + j];
                const float dj1 = D[dS + ((j + 1) & mm)];
                const float dj2 = D[dS + ((j + 2) & mm)];
                const float aj  = aprevW[j];
                const float aj1 = aprevW[(j + 1) & mm];
                const float aj2 = aprevW[(j + 2) & mm];
                recW[2*j]     = g0*dj  + g2*dj1 + h0*aj  + h2*aj1;
                recW[2*j + 1] = g1*dj1 + g3*dj2 + h1*aj1 + h3*aj2;
            }
            __builtin_amdgcn_wave_barrier();
            aprevW = recW; mS <<= 1; dS -= mS;
        }
    }
    __syncthreads();   // FULL drain: coeff stores must be visible before re-read
    // lev4 rec (512) now in C

    // ---------------- synthesis levels 3..0 (all threads, 4 out/thread) -----
    // rec[2j]   = g0*d[j]   + g2*d[j+1] + h0*a[j]   + h2*a[j+1]
    // rec[2j+1] = g1*d[j+1] + g3*d[j+2] + h1*a[j+1] + h3*a[j+2]   (mod m)
#define SYNTH_BODY(d2)                                                        \
    for (int p = tid; p < mp; p += TPB) {                                     \
        const float2 dv0 = (d2)[p];                                           \
        const float2 dv1 = (d2)[(p + 1) & mm];                                \
        const float2 av0 = a2[p];                                             \
        const float2 av1 = a2[(p + 1) & mm];                                  \
        const float r0 = g0*dv0.x + g2*dv0.y + h0*av0.x + h2*av0.y;           \
        const float r1 = g1*dv0.y + g3*dv1.x + h1*av0.y + h3*av1.x;           \
        const float r2 = g0*dv0.y + g2*dv1.x + h0*av0.y + h2*av1.x;           \
        const float r3 = g1*dv1.x + g3*dv1.y + h1*av1.x + h3*av1.y;           \
        const float4 rv = make_float4(r0, r1, r2, r3);                        \
        if (last) reinterpret_cast<float4*>(out_rec)[p] = rv;                 \
        else      reinterpret_cast<float4*>(rec)[p]     = rv;                 \
    }

    const float* aprev = C;
    int m = 512;
    for (int lev = 3; lev >= 0; --lev) {
        const float h0 = filt[4*lev+0], h1 = filt[4*lev+1],
                    h2 = filt[4*lev+2], h3 = filt[4*lev+3];
        const float g0 = h3, g1 = -h2, g2 = h1, g3 = -h0;
        const int mp = m >> 1, mm = mp - 1;
        const float2* a2 = reinterpret_cast<const float2*>(aprev);
        float* rec = (lev & 1) ? B : C;   // lev3->B lev2->C lev1->B
        const bool last = (lev == 0);
        if (lev >= 2) {
            const float2* dL = reinterpret_cast<const float2*>(D + ((lev == 3) ? 1024 : 0));
            SYNTH_BODY(dL)
        } else {
            const float2* __restrict__ dG =
                reinterpret_cast<const float2*>(out_coef + ((lev == 1) ? 4096 : 0));
            SYNTH_BODY(dG)
        }
        if (lev) bar_lds();
        aprev = rec; m <<= 1;
    }
#undef SYNTH_BODY
}

extern "C" void kernel_launch(void* const* d_in, const int* in_sizes, int n_in,
                              void* d_out, int out_size, void* d_ws, size_t ws_size,
                              hipStream_t stream) {
    const float* x       = (const float*)d_in[0];
    const float* scaling = (const float*)d_in[1];
    float* out           = (float*)d_out;
    const int rows = in_sizes[0] / COLS;
    despawn_kernel<<<rows, TPB, 0, stream>>>(x, scaling, out, rows);
}